// Round 1
// baseline (339.475 us; speedup 1.0000x reference)
//
#include <hip/hip_runtime.h>

// Problem constants (fixed by setup_inputs)
#define BB 2
#define NN 16384
#define CC 64
#define SS 4096
#define KK 32
#define R2 0.16f   // RADIUS^2 = 0.4^2

// ---------------------------------------------------------------------------
// Kernel A: ball query (first-32-in-index-order within radius), plus new_xyz
// and samp_idx outputs. One wave (64 threads) per centroid.
// ---------------------------------------------------------------------------
__global__ __launch_bounds__(64) void bq_kernel(const float* __restrict__ xyz,
                                                float* __restrict__ out_xyz,
                                                float* __restrict__ out_sidx,
                                                int* __restrict__ idx_ws) {
    const int bs = blockIdx.x;        // 0 .. BB*SS-1
    const int b = bs >> 12;           // / 4096
    const int s = bs & (SS - 1);
    const int lane = threadIdx.x;

    __shared__ int hit_idx[KK];

    const float* xb = xyz + (size_t)b * NN * 3;
    const float cx = xb[s * 3 + 0];
    const float cy = xb[s * 3 + 1];
    const float cz = xb[s * 3 + 2];
    const float cs = cx * cx + cy * cy + cz * cz;

    int cnt = 0;  // wave-uniform (derived from ballot)
    for (int base = 0; base < NN; base += 64) {
        const int n = base + lane;
        const float x = xb[n * 3 + 0];
        const float y = xb[n * 3 + 1];
        const float z = xb[n * 3 + 2];
        const float xs = x * x + y * y + z * z;
        const float cross = cx * x + cy * y + cz * z;
        const float d2 = cs + xs - 2.0f * cross;   // same expansion as reference
        const bool hit = d2 < R2;
        const unsigned long long m = __ballot(hit);
        if (hit) {
            const int pos = cnt + (int)__popcll(m & ((1ull << lane) - 1ull));
            if (pos < KK) hit_idx[pos] = n;
        }
        cnt += (int)__popcll(m);
        if (cnt >= KK) break;   // uniform branch
    }
    __syncthreads();

    if (lane < KK) {
        int v;
        if (cnt == 0) v = 0;                       // no hit anywhere -> 0
        else v = (lane < cnt) ? hit_idx[lane] : hit_idx[0];  // pad w/ first hit
        idx_ws[bs * KK + lane] = v;
    } else if (lane < 35) {
        const int d = lane - 32;
        out_xyz[bs * 3 + d] = xb[s * 3 + d];
    } else if (lane == 35) {
        out_sidx[bs] = (float)s;                   // samp_idx stored as float
    }
}

// ---------------------------------------------------------------------------
// Kernel B: gather + 3-layer MLP + maxpool. One 256-thread block per (b,s).
// Per-wave neighbor-subset ownership makes LDS reads wave-uniform broadcasts;
// per-lane channel ownership makes weight reads coalesced (L1/L2-hot).
// ---------------------------------------------------------------------------
__global__ __launch_bounds__(256) void mlp_kernel(
        const float* __restrict__ xyz, const float* __restrict__ feat,
        const float* __restrict__ W1, const float* __restrict__ b1,
        const float* __restrict__ W2, const float* __restrict__ b2,
        const float* __restrict__ W3, const float* __restrict__ b3,
        const int* __restrict__ idx_ws, float* __restrict__ out_feat) {
    const int bs = blockIdx.x;
    const int b = bs >> 12;
    const int s = bs & (SS - 1);
    const int t = threadIdx.x;

    __shared__ int   kidx[KK];
    __shared__ float g[KK][68];     // 67 cols + zero pad, rows 272B (16B-aligned)
    __shared__ float h1s[KK][64];
    __shared__ float h2s[KK][64];
    __shared__ float pmax[2][128];

    if (t < KK) kidx[t] = idx_ws[bs * KK + t];
    __syncthreads();

    // ---- stage g[k][0..66] = [rel_xyz(3) | features(64)] -------------------
    {
        const int k = t >> 3;       // 0..31
        const int j = t & 7;
        const int id = kidx[k];
        const float* xb = xyz + (size_t)b * NN * 3;
        const float* fb = feat + (size_t)b * CC * NN;
        for (int c = j; c < 67; c += 8) {
            float v;
            if (c < 3) v = xb[id * 3 + c] - xb[s * 3 + c];
            else       v = fb[(c - 3) * NN + id];
            g[k][c] = v;
        }
        if (j == 0) g[k][67] = 0.0f;
    }
    __syncthreads();

    // ---- layer 1: h1[k][d] = relu(sum_c g[k][c] * W1[c][d] + b1[d]) --------
    {
        const int d = t & 63;
        const int kb = (t >> 6) * 8;    // wave-uniform
        float acc[8] = {0, 0, 0, 0, 0, 0, 0, 0};
        for (int c4 = 0; c4 < 17; ++c4) {
            const int c = c4 * 4;
            const float w0 = W1[(c + 0) * 64 + d];
            const float w1 = W1[(c + 1) * 64 + d];
            const float w2 = W1[(c + 2) * 64 + d];
            const float w3 = (c + 3 < 67) ? W1[(c + 3) * 64 + d] : 0.0f;
            #pragma unroll
            for (int k = 0; k < 8; ++k) {
                const float4 gv = *reinterpret_cast<const float4*>(&g[kb + k][c]);
                acc[k] += gv.x * w0 + gv.y * w1 + gv.z * w2 + gv.w * w3;
            }
        }
        const float bias = b1[d];
        #pragma unroll
        for (int k = 0; k < 8; ++k) h1s[kb + k][d] = fmaxf(acc[k] + bias, 0.0f);
    }
    __syncthreads();

    // ---- layer 2: 64 -> 64 -------------------------------------------------
    {
        const int d = t & 63;
        const int kb = (t >> 6) * 8;
        float acc[8] = {0, 0, 0, 0, 0, 0, 0, 0};
        for (int c4 = 0; c4 < 16; ++c4) {
            const int c = c4 * 4;
            const float w0 = W2[(c + 0) * 64 + d];
            const float w1 = W2[(c + 1) * 64 + d];
            const float w2 = W2[(c + 2) * 64 + d];
            const float w3 = W2[(c + 3) * 64 + d];
            #pragma unroll
            for (int k = 0; k < 8; ++k) {
                const float4 hv = *reinterpret_cast<const float4*>(&h1s[kb + k][c]);
                acc[k] += hv.x * w0 + hv.y * w1 + hv.z * w2 + hv.w * w3;
            }
        }
        const float bias = b2[d];
        #pragma unroll
        for (int k = 0; k < 8; ++k) h2s[kb + k][d] = fmaxf(acc[k] + bias, 0.0f);
    }
    __syncthreads();

    // ---- layer 3: 64 -> 128, fused partial maxpool -------------------------
    {
        const int d = t & 127;
        const int kg = t >> 7;          // 0 or 1 (wave-uniform)
        const int kb = kg * 16;
        float acc[16];
        #pragma unroll
        for (int k = 0; k < 16; ++k) acc[k] = 0.0f;
        for (int c4 = 0; c4 < 16; ++c4) {
            const int c = c4 * 4;
            const float w0 = W3[(c + 0) * 128 + d];
            const float w1 = W3[(c + 1) * 128 + d];
            const float w2 = W3[(c + 2) * 128 + d];
            const float w3 = W3[(c + 3) * 128 + d];
            #pragma unroll
            for (int k = 0; k < 16; ++k) {
                const float4 hv = *reinterpret_cast<const float4*>(&h2s[kb + k][c]);
                acc[k] += hv.x * w0 + hv.y * w1 + hv.z * w2 + hv.w * w3;
            }
        }
        const float bias = b3[d];
        float m = -1e30f;
        #pragma unroll
        for (int k = 0; k < 16; ++k) m = fmaxf(m, acc[k] + bias);
        pmax[kg][d] = m;
    }
    __syncthreads();

    // ---- combine + relu + transposed store [B,128,S] -----------------------
    if (t < 128) {
        const float v = fmaxf(fmaxf(pmax[0][t], pmax[1][t]), 0.0f);
        out_feat[((size_t)b * 128 + t) * SS + s] = v;
    }
}

// ---------------------------------------------------------------------------
extern "C" void kernel_launch(void* const* d_in, const int* in_sizes, int n_in,
                              void* d_out, int out_size, void* d_ws, size_t ws_size,
                              hipStream_t stream) {
    const float* xyz  = (const float*)d_in[0];
    const float* feat = (const float*)d_in[1];
    const float* W1   = (const float*)d_in[2];
    const float* b1   = (const float*)d_in[3];
    const float* W2   = (const float*)d_in[4];
    const float* b2   = (const float*)d_in[5];
    const float* W3   = (const float*)d_in[6];
    const float* b3   = (const float*)d_in[7];

    float* out      = (float*)d_out;
    float* out_xyz  = out;                               // [2,4096,3]
    float* out_feat = out + (size_t)BB * SS * 3;         // [2,128,4096]
    float* out_sidx = out_feat + (size_t)BB * 128 * SS;  // [2,4096] as float

    int* idx_ws = (int*)d_ws;                            // [2,4096,32] int32

    bq_kernel<<<BB * SS, 64, 0, stream>>>(xyz, out_xyz, out_sidx, idx_ws);
    mlp_kernel<<<BB * SS, 256, 0, stream>>>(xyz, feat, W1, b1, W2, b2, W3, b3,
                                            idx_ws, out_feat);
}

// Round 2
// 182.216 us; speedup vs baseline: 1.8630x; 1.8630x over previous
//
#include <hip/hip_runtime.h>

#define BB 2
#define NN 16384
#define CC 64
#define SS 4096
#define KK 32
#define R2 0.16f   // RADIUS^2

typedef __bf16 bf16x8 __attribute__((ext_vector_type(8)));
typedef float  f32x4  __attribute__((ext_vector_type(4)));

#define MFMA(a, b, c) __builtin_amdgcn_mfma_f32_16x16x32_bf16((a), (b), (c), 0, 0, 0)

static __device__ __forceinline__ ushort f2bf(float f) {
    __bf16 h = (__bf16)f;
    return *(ushort*)&h;
}

// ---------------------------------------------------------------------------
// prep_misc: pts4 = (x,y,z,|x|^2); weight transposes to bf16 n-major.
// W1t[n][k]: k 0..63 -> W1[3+k][n] (features), k 64..66 -> W1[k-64][n] (xyz),
//            k 67..95 -> 0.  W2t[n][k] = W2[k][n].  W3t[n][k] = W3[k][n].
// ---------------------------------------------------------------------------
__global__ __launch_bounds__(256) void prep_misc(
        const float* __restrict__ xyz, const float* __restrict__ W1,
        const float* __restrict__ W2, const float* __restrict__ W3,
        float4* __restrict__ pts4, ushort* __restrict__ W1t,
        ushort* __restrict__ W2t, ushort* __restrict__ W3t) {
    const int t = blockIdx.x * 256 + threadIdx.x;
    if (t < BB * NN) {
        const float* p = xyz + (size_t)t * 3;
        const float x = p[0], y = p[1], z = p[2];
        pts4[t] = make_float4(x, y, z, x * x + y * y + z * z);
    } else if (t < BB * NN + 64 * 96) {
        const int i = t - BB * NN;
        const int n = i / 96, k = i - n * 96;
        float v = 0.0f;
        if (k < 64) v = W1[(3 + k) * 64 + n];
        else if (k < 67) v = W1[(k - 64) * 64 + n];
        W1t[n * 96 + k] = f2bf(v);
    } else if (t < BB * NN + 64 * 96 + 64 * 64) {
        const int i = t - BB * NN - 64 * 96;
        const int n = i >> 6, k = i & 63;
        W2t[n * 64 + k] = f2bf(W2[k * 64 + n]);
    } else if (t < BB * NN + 64 * 96 + 64 * 64 + 128 * 64) {
        const int i = t - BB * NN - 64 * 96 - 64 * 64;
        const int n = i >> 6, k = i & 63;
        W3t[n * 64 + k] = f2bf(W3[k * 128 + n]);
    }
}

// ---------------------------------------------------------------------------
// prep_feat: [B][C][N] fp32 -> [B][N][C] bf16. Coalesced reads per channel.
// ---------------------------------------------------------------------------
__global__ __launch_bounds__(256) void prep_feat(const float* __restrict__ feat,
                                                 ushort* __restrict__ feat_nc) {
    const int t = blockIdx.x * 256 + threadIdx.x;   // 0 .. BB*NN-1
    const int b = t >> 14, n = t & (NN - 1);
    const float* fb = feat + (size_t)b * CC * NN + n;
    ushort* dst = feat_nc + (size_t)t * 64;
    #pragma unroll
    for (int c8 = 0; c8 < 8; ++c8) {
        uint u[4];
        #pragma unroll
        for (int j = 0; j < 4; ++j) {
            const float f0 = fb[(size_t)(c8 * 8 + 2 * j) * NN];
            const float f1 = fb[(size_t)(c8 * 8 + 2 * j + 1) * NN];
            u[j] = (uint)f2bf(f0) | ((uint)f2bf(f1) << 16);
        }
        *(uint4*)(dst + c8 * 8) = make_uint4(u[0], u[1], u[2], u[3]);
    }
}

// ---------------------------------------------------------------------------
// bq: one wave per centroid, 4 waves/block, 2-chunk unrolled float4 scan.
// ---------------------------------------------------------------------------
__global__ __launch_bounds__(256) void bq_kernel(const float4* __restrict__ pts4,
                                                 float* __restrict__ out_xyz,
                                                 float* __restrict__ out_sidx,
                                                 int* __restrict__ idx_ws) {
    const int w = threadIdx.x >> 6, lane = threadIdx.x & 63;
    const int bs = blockIdx.x * 4 + w;
    const int b = bs >> 12, s = bs & (SS - 1);

    __shared__ int hits[4][KK];
    int* hit = hits[w];

    const float4* pb = pts4 + (size_t)b * NN;
    const float4 c = pb[s];
    const unsigned long long ltmask = (1ull << lane) - 1ull;

    int cnt = 0;
    for (int base = 0; base < NN; base += 128) {
        const float4 p0 = pb[base + lane];
        const float4 p1 = pb[base + 64 + lane];
        const float d0 = c.w + p0.w - 2.0f * (c.x * p0.x + c.y * p0.y + c.z * p0.z);
        const float d1 = c.w + p1.w - 2.0f * (c.x * p1.x + c.y * p1.y + c.z * p1.z);
        const bool h0 = d0 < R2, h1 = d1 < R2;
        const unsigned long long m0 = __ballot(h0);
        const unsigned long long m1 = __ballot(h1);
        const int c0 = __popcll(m0);
        if (h0) {
            const int pos = cnt + __popcll(m0 & ltmask);
            if (pos < KK) hit[pos] = base + lane;
        }
        if (h1) {
            const int pos = cnt + c0 + __popcll(m1 & ltmask);
            if (pos < KK) hit[pos] = base + 64 + lane;
        }
        cnt += c0 + __popcll(m1);
        if (cnt >= KK) break;   // wave-uniform
    }

    if (lane < KK) {
        const int v = (cnt == 0) ? 0 : ((lane < cnt) ? hit[lane] : hit[0]);
        idx_ws[bs * KK + lane] = v;
    } else if (lane < 35) {
        const int d = lane - 32;
        out_xyz[bs * 3 + d] = (d == 0) ? c.x : ((d == 1) ? c.y : c.z);
    } else if (lane == 35) {
        out_sidx[bs] = (float)s;
    }
}

// ---------------------------------------------------------------------------
// mlp: one wave per group (grid-stride). W1/W2 B-frags pinned in registers,
// per-wave LDS staging, 72 MFMA/group, fused bias (acc init) + maxpool.
// g layout per row (stride 104 bf16): [feat 0..63 | relxyz 64..66 | 0 .. 95]
// ---------------------------------------------------------------------------
__global__ __launch_bounds__(256, 2) void mlp_kernel(
        const float4* __restrict__ pts4, const ushort* __restrict__ feat_nc,
        const ushort* __restrict__ W1t, const ushort* __restrict__ W2t,
        const ushort* __restrict__ W3t,
        const float* __restrict__ b1, const float* __restrict__ b2,
        const float* __restrict__ b3,
        const int* __restrict__ idx_ws, float* __restrict__ out_feat) {
    const int w = threadIdx.x >> 6, lane = threadIdx.x & 63;
    const int quad = lane >> 4, mrow = lane & 15;

    // per-wave LDS; strides 104/72 bf16 stagger bank starts (2-way max)
    __shared__ __align__(16) ushort ldsA[4][32 * 104];  // g, reused as h2
    __shared__ __align__(16) ushort ldsB[4][32 * 72];   // h1
    ushort* gbuf = ldsA[w];
    ushort* hbuf = ldsB[w];

    // B-fragments held in registers for the whole kernel
    bf16x8 w1f[4][3], w2f[4][2];
    #pragma unroll
    for (int nt = 0; nt < 4; ++nt) {
        #pragma unroll
        for (int ks = 0; ks < 3; ++ks)
            w1f[nt][ks] = *(const bf16x8*)(W1t + (nt * 16 + mrow) * 96 + ks * 32 + quad * 8);
        #pragma unroll
        for (int ks = 0; ks < 2; ++ks)
            w2f[nt][ks] = *(const bf16x8*)(W2t + (nt * 16 + mrow) * 64 + ks * 32 + quad * 8);
    }
    float bias1[4], bias2[4], bias3[8];
    #pragma unroll
    for (int nt = 0; nt < 4; ++nt) {
        bias1[nt] = b1[nt * 16 + mrow];
        bias2[nt] = b2[nt * 16 + mrow];
    }
    #pragma unroll
    for (int nt = 0; nt < 8; ++nt) bias3[nt] = b3[nt * 16 + mrow];

    const int wid = blockIdx.x * 4 + w;
    for (int grp = wid; grp < BB * SS; grp += gridDim.x * 4) {
        const int b = grp >> 12, s = grp & (SS - 1);

        // ---- gather: features (bf16 copy) + rel_xyz + zero pad -------------
        {
            const int m = lane & 31, half = lane >> 5;
            const int id = idx_ws[grp * KK + m];
            const ushort* src = feat_nc + ((size_t)b * NN + id) * 64 + half * 32;
            ushort* dst = gbuf + m * 104 + half * 32;
            #pragma unroll
            for (int i = 0; i < 4; ++i)
                *(uint4*)(dst + i * 8) = *(const uint4*)(src + i * 8);
            if (half == 0) {
                const float4 p = pts4[(size_t)b * NN + id];
                const float4 c = pts4[(size_t)b * NN + s];
                bf16x8 rel = {(__bf16)(p.x - c.x), (__bf16)(p.y - c.y),
                              (__bf16)(p.z - c.z), (__bf16)0.f,
                              (__bf16)0.f, (__bf16)0.f, (__bf16)0.f, (__bf16)0.f};
                *(bf16x8*)(gbuf + m * 104 + 64) = rel;
                *(uint4*)(gbuf + m * 104 + 88) = make_uint4(0, 0, 0, 0);
            } else {
                *(uint4*)(gbuf + m * 104 + 72) = make_uint4(0, 0, 0, 0);
                *(uint4*)(gbuf + m * 104 + 80) = make_uint4(0, 0, 0, 0);
            }
        }

        // ---- layer 1: [32x96]x[96x64] ---------------------------------------
        f32x4 acc1[2][4];
        #pragma unroll
        for (int mt = 0; mt < 2; ++mt)
            #pragma unroll
            for (int nt = 0; nt < 4; ++nt)
                acc1[mt][nt] = (f32x4){bias1[nt], bias1[nt], bias1[nt], bias1[nt]};
        #pragma unroll
        for (int ks = 0; ks < 3; ++ks) {
            const bf16x8 a0 = *(const bf16x8*)(gbuf + mrow * 104 + ks * 32 + quad * 8);
            const bf16x8 a1 = *(const bf16x8*)(gbuf + (16 + mrow) * 104 + ks * 32 + quad * 8);
            #pragma unroll
            for (int nt = 0; nt < 4; ++nt) {
                acc1[0][nt] = MFMA(a0, w1f[nt][ks], acc1[0][nt]);
                acc1[1][nt] = MFMA(a1, w1f[nt][ks], acc1[1][nt]);
            }
        }
        // relu -> bf16 -> hbuf (A-layout, stride 72)
        #pragma unroll
        for (int mt = 0; mt < 2; ++mt)
            #pragma unroll
            for (int nt = 0; nt < 4; ++nt)
                #pragma unroll
                for (int r = 0; r < 4; ++r)
                    hbuf[(mt * 16 + quad * 4 + r) * 72 + nt * 16 + mrow] =
                        f2bf(fmaxf(acc1[mt][nt][r], 0.0f));

        // ---- layer 2: [32x64]x[64x64] ---------------------------------------
        f32x4 acc2[2][4];
        #pragma unroll
        for (int mt = 0; mt < 2; ++mt)
            #pragma unroll
            for (int nt = 0; nt < 4; ++nt)
                acc2[mt][nt] = (f32x4){bias2[nt], bias2[nt], bias2[nt], bias2[nt]};
        #pragma unroll
        for (int ks = 0; ks < 2; ++ks) {
            const bf16x8 a0 = *(const bf16x8*)(hbuf + mrow * 72 + ks * 32 + quad * 8);
            const bf16x8 a1 = *(const bf16x8*)(hbuf + (16 + mrow) * 72 + ks * 32 + quad * 8);
            #pragma unroll
            for (int nt = 0; nt < 4; ++nt) {
                acc2[0][nt] = MFMA(a0, w2f[nt][ks], acc2[0][nt]);
                acc2[1][nt] = MFMA(a1, w2f[nt][ks], acc2[1][nt]);
            }
        }
        // relu -> bf16 -> gbuf (reuse, stride 104, cols 0..63)
        #pragma unroll
        for (int mt = 0; mt < 2; ++mt)
            #pragma unroll
            for (int nt = 0; nt < 4; ++nt)
                #pragma unroll
                for (int r = 0; r < 4; ++r)
                    gbuf[(mt * 16 + quad * 4 + r) * 104 + nt * 16 + mrow] =
                        f2bf(fmaxf(acc2[mt][nt][r], 0.0f));

        // ---- layer 3: [32x64]x[64x128], W3 frags streamed from L1 -----------
        f32x4 acc3[2][8];
        #pragma unroll
        for (int mt = 0; mt < 2; ++mt)
            #pragma unroll
            for (int nt = 0; nt < 8; ++nt)
                acc3[mt][nt] = (f32x4){bias3[nt], bias3[nt], bias3[nt], bias3[nt]};
        #pragma unroll
        for (int ks = 0; ks < 2; ++ks) {
            const bf16x8 a0 = *(const bf16x8*)(gbuf + mrow * 104 + ks * 32 + quad * 8);
            const bf16x8 a1 = *(const bf16x8*)(gbuf + (16 + mrow) * 104 + ks * 32 + quad * 8);
            #pragma unroll
            for (int nt = 0; nt < 8; ++nt) {
                const bf16x8 w3f = *(const bf16x8*)(W3t + (nt * 16 + mrow) * 64 + ks * 32 + quad * 8);
                acc3[0][nt] = MFMA(a0, w3f, acc3[0][nt]);
                acc3[1][nt] = MFMA(a1, w3f, acc3[1][nt]);
            }
        }

        // ---- maxpool over 32 rows + relu + store ----------------------------
        #pragma unroll
        for (int nt = 0; nt < 8; ++nt) {
            const f32x4 v0 = acc3[0][nt], v1 = acc3[1][nt];
            float mx = fmaxf(fmaxf(v0[0], v0[1]), fmaxf(v0[2], v0[3]));
            mx = fmaxf(mx, fmaxf(fmaxf(v1[0], v1[1]), fmaxf(v1[2], v1[3])));
            mx = fmaxf(mx, __shfl_xor(mx, 16));
            mx = fmaxf(mx, __shfl_xor(mx, 32));
            mx = fmaxf(mx, 0.0f);
            if (quad == 0)
                out_feat[((size_t)b * 128 + nt * 16 + mrow) * SS + s] = mx;
        }
    }
}

// ---------------------------------------------------------------------------
extern "C" void kernel_launch(void* const* d_in, const int* in_sizes, int n_in,
                              void* d_out, int out_size, void* d_ws, size_t ws_size,
                              hipStream_t stream) {
    const float* xyz  = (const float*)d_in[0];
    const float* feat = (const float*)d_in[1];
    const float* W1   = (const float*)d_in[2];
    const float* b1   = (const float*)d_in[3];
    const float* W2   = (const float*)d_in[4];
    const float* b2   = (const float*)d_in[5];
    const float* W3   = (const float*)d_in[6];
    const float* b3   = (const float*)d_in[7];

    float* out      = (float*)d_out;
    float* out_xyz  = out;                               // [2,4096,3]
    float* out_feat = out + (size_t)BB * SS * 3;         // [2,128,4096]
    float* out_sidx = out_feat + (size_t)BB * 128 * SS;  // [2,4096]

    // workspace layout (16B-aligned sections)
    char* ws = (char*)d_ws;
    int*    idx_ws  = (int*)ws;                          // 1,048,576 B
    float4* pts4    = (float4*)(ws + 1048576);           //   524,288 B
    ushort* feat_nc = (ushort*)(ws + 1572864);           // 4,194,304 B
    ushort* W1t     = (ushort*)(ws + 5767168);           //    12,288 B
    ushort* W2t     = (ushort*)(ws + 5779456);           //     8,192 B
    ushort* W3t     = (ushort*)(ws + 5787648);           //    16,384 B

    prep_misc<<<(BB * NN + 64 * 96 + 64 * 64 + 128 * 64 + 255) / 256, 256, 0, stream>>>(
        xyz, W1, W2, W3, pts4, W1t, W2t, W3t);
    prep_feat<<<BB * NN / 256, 256, 0, stream>>>(feat, feat_nc);
    bq_kernel<<<BB * SS / 4, 256, 0, stream>>>(pts4, out_xyz, out_sidx, idx_ws);
    mlp_kernel<<<1024, 256, 0, stream>>>(pts4, feat_nc, W1t, W2t, W3t,
                                         b1, b2, b3, idx_ws, out_feat);
}